// Round 1
// baseline (860.995 us; speedup 1.0000x reference)
//
#include <hip/hip_runtime.h>
#include <hip/hip_bf16.h>
#include <math.h>

// Problem: B=128, S=2048, H=512, A=512. M = B*S = 262144 tokens.
// out = (output [128,512], alphas [128,2048]) fp32, concatenated: 65536 + 262144.

#define M_TOK 262144
#define HDIM 512
#define ADIM 512
#define SDIM 2048
#define BDIM 128

typedef __attribute__((ext_vector_type(8))) short short8;   // 8 bf16 (4 VGPRs)
typedef __attribute__((ext_vector_type(4))) float f32x4;    // 4 fp32 acc

static __device__ __forceinline__ unsigned short f2bf(float f) {
    // round-to-nearest-even fp32 -> bf16
    unsigned u = __builtin_bit_cast(unsigned, f);
    unsigned rnd = 0x7FFFu + ((u >> 16) & 1u);
    return (unsigned short)((u + rnd) >> 16);
}

// ---------------------------------------------------------------------------
// k0: convert W [512][512] fp32 -> bf16, pre-swizzled into 16x16x32 B-fragment
// order. Fragment (kb, nb): 64 lanes x 8 bf16, lane holds W[kb*32 + (lane>>4)*8
// + j][nb*16 + (lane&15)], j=0..7 contiguous. One thread per (frag, lane).
// ---------------------------------------------------------------------------
__global__ void k_wswz(const float* __restrict__ W, unsigned short* __restrict__ Wswz) {
    int t = blockIdx.x * 256 + threadIdx.x;   // 32768 threads total
    int lane = t & 63;
    int frag = t >> 6;                        // 0..511: frag = kb*32 + nb
    int kb = frag >> 5;
    int nb = frag & 31;
    int n  = nb * 16 + (lane & 15);
    int k0 = kb * 32 + (lane >> 4) * 8;
    short8 s;
#pragma unroll
    for (int j = 0; j < 8; ++j)
        s[j] = (short)f2bf(W[(k0 + j) * ADIM + n]);
    reinterpret_cast<short8*>(Wswz)[t] = s;   // frag*64 + lane == t
}

// ---------------------------------------------------------------------------
// k1: fused GEMM + tanh + dot(u) -> vu[M].  64 token-rows per block.
// X tile staged bf16 in LDS (pad +8 shorts to break bank aliasing).
// 4 waves split the N=512 columns (128 each): per wave 4 (M) x 8 (N) C-frags.
// B-fragments streamed from pre-swizzled Wswz (global, L2-resident), one
// K-step prefetch ahead.
// ---------------------------------------------------------------------------
__global__ __launch_bounds__(256, 2)
void k_gemm_vu(const float* __restrict__ X, const unsigned short* __restrict__ Wswz,
               const float* __restrict__ bvec, const float* __restrict__ u,
               float* __restrict__ vu) {
    __shared__ __align__(16) unsigned short Xs[64][520];
    __shared__ float vured[4][64];

    const int tid  = threadIdx.x;
    const int lane = tid & 63;
    const int wave = tid >> 6;
    const int lm   = lane & 15;
    const int quad = lane >> 4;
    const int r0   = blockIdx.x * 64;

    // ---- stage X[r0:r0+64][0:512] fp32 -> bf16 LDS ----
    const float4* Xp = reinterpret_cast<const float4*>(X + (size_t)r0 * HDIM);
#pragma unroll 8
    for (int it = 0; it < 32; ++it) {
        int idx  = it * 256 + tid;        // float4 index within tile (coalesced)
        int row  = idx >> 7;              // /128 float4 per row
        int col4 = idx & 127;
        float4 v = Xp[idx];
        unsigned lo = (unsigned)f2bf(v.x) | ((unsigned)f2bf(v.y) << 16);
        unsigned hi = (unsigned)f2bf(v.z) | ((unsigned)f2bf(v.w) << 16);
        unsigned* d = reinterpret_cast<unsigned*>(&Xs[row][col4 * 4]);
        d[0] = lo; d[1] = hi;
    }
    __syncthreads();

    // B-frag base for this wave: frag index (kb*32 + wave*8 + j)*64 + lane
    const short8* wbl = reinterpret_cast<const short8*>(Wswz) + lane + wave * 512;

    f32x4 acc[4][8];
#pragma unroll
    for (int i = 0; i < 4; ++i)
#pragma unroll
        for (int j = 0; j < 8; ++j)
            acc[i][j] = (f32x4){0.f, 0.f, 0.f, 0.f};

    short8 bcur[8], bnxt[8];
#pragma unroll
    for (int j = 0; j < 8; ++j) bcur[j] = wbl[j * 64];

    for (int kb = 0; kb < 16; ++kb) {
        if (kb < 15) {
#pragma unroll
            for (int j = 0; j < 8; ++j) bnxt[j] = wbl[(kb + 1) * 2048 + j * 64];
        }
        short8 a[4];
#pragma unroll
        for (int i = 0; i < 4; ++i)
            a[i] = *reinterpret_cast<const short8*>(&Xs[i * 16 + lm][kb * 32 + quad * 8]);
#pragma unroll
        for (int i = 0; i < 4; ++i)
#pragma unroll
            for (int j = 0; j < 8; ++j)
                acc[i][j] = __builtin_amdgcn_mfma_f32_16x16x32_bf16(a[i], bcur[j], acc[i][j], 0, 0, 0);
#pragma unroll
        for (int j = 0; j < 8; ++j) bcur[j] = bnxt[j];
    }

    // ---- epilogue: tanh(acc + b) dot u, reduce to per-row vu ----
    float vus[16];
#pragma unroll
    for (int q = 0; q < 16; ++q) vus[q] = 0.f;
    const int colbase = wave * 128 + lm;
#pragma unroll
    for (int j = 0; j < 8; ++j) {
        int col  = colbase + j * 16;
        float uu = u[col];
        float bb = bvec[col];
#pragma unroll
        for (int i = 0; i < 4; ++i)
#pragma unroll
            for (int r = 0; r < 4; ++r) {
                float x = acc[i][j][r] + bb;
                float e = __expf(2.0f * x);       // inf-safe tanh form
                float t = 1.0f - 2.0f / (e + 1.0f);
                vus[i * 4 + r] += t * uu;
            }
    }
    // butterfly-reduce across the 16 column-lanes (low 4 lane bits)
#pragma unroll
    for (int m = 1; m <= 8; m <<= 1) {
#pragma unroll
        for (int q = 0; q < 16; ++q)
            vus[q] += __shfl_xor(vus[q], m, 64);
    }
    if (lm == 0) {
#pragma unroll
        for (int i = 0; i < 4; ++i)
#pragma unroll
            for (int r = 0; r < 4; ++r)
                vured[wave][i * 16 + quad * 4 + r] = vus[i * 4 + r];
    }
    __syncthreads();
    if (tid < 64) {
        float s = vured[0][tid] + vured[1][tid] + vured[2][tid] + vured[3][tid];
        vu[r0 + tid] = s * 0.044194173824159216f;   // 1/sqrt(512)
    }
}

// ---------------------------------------------------------------------------
// k2: per-batch softmax over S=2048, in place in the alphas slot of d_out.
// ---------------------------------------------------------------------------
__global__ void k_softmax(float* __restrict__ out) {
    float* vu = out + 65536 + (size_t)blockIdx.x * SDIM;
    const int tid  = threadIdx.x;
    const int lane = tid & 63;
    const int wave = tid >> 6;
    __shared__ float red[8];

    float v[8];
#pragma unroll
    for (int i = 0; i < 8; ++i) v[i] = vu[tid + 256 * i];

    float mx = v[0];
#pragma unroll
    for (int i = 1; i < 8; ++i) mx = fmaxf(mx, v[i]);
#pragma unroll
    for (int m = 1; m <= 32; m <<= 1) mx = fmaxf(mx, __shfl_xor(mx, m, 64));
    if (lane == 0) red[wave] = mx;
    __syncthreads();
    mx = fmaxf(fmaxf(red[0], red[1]), fmaxf(red[2], red[3]));

    float e[8], s = 0.f;
#pragma unroll
    for (int i = 0; i < 8; ++i) { e[i] = __expf(v[i] - mx); s += e[i]; }
#pragma unroll
    for (int m = 1; m <= 32; m <<= 1) s += __shfl_xor(s, m, 64);
    if (lane == 0) red[4 + wave] = s;
    __syncthreads();
    s = red[4] + red[5] + red[6] + red[7];

    float invs = 1.0f / (s + 1e-10f);
#pragma unroll
    for (int i = 0; i < 8; ++i) vu[tid + 256 * i] = e[i] * invs;
}

// ---------------------------------------------------------------------------
// k3: output[b,h] = sum_s alphas[b,s] * X[b,s,h]. 8 s-chunks per batch,
// partials atomically added into the memset-zeroed output slot.
// ---------------------------------------------------------------------------
__global__ __launch_bounds__(256)
void k_wsum(const float* __restrict__ X, float* __restrict__ out) {
    const int blk = blockIdx.x;
    const int b   = blk >> 3;
    const int sc  = blk & 7;
    const float* alp = out + 65536 + (size_t)b * SDIM + sc * 256;
    const float* xb  = X + ((size_t)b * SDIM + sc * 256) * HDIM;
    const int tid = threadIdx.x;
    float a0 = 0.f, a1 = 0.f;
#pragma unroll 4
    for (int s = 0; s < 256; ++s) {
        float al = alp[s];
        a0 = fmaf(al, xb[(size_t)s * HDIM + tid], a0);
        a1 = fmaf(al, xb[(size_t)s * HDIM + tid + 256], a1);
    }
    atomicAdd(&out[b * HDIM + tid], a0);
    atomicAdd(&out[b * HDIM + tid + 256], a1);
}

extern "C" void kernel_launch(void* const* d_in, const int* in_sizes, int n_in,
                              void* d_out, int out_size, void* d_ws, size_t ws_size,
                              hipStream_t stream) {
    const float* X  = (const float*)d_in[0];   // [128,2048,512]
    const float* W  = (const float*)d_in[1];   // [512,512]
    const float* bb = (const float*)d_in[2];   // [512]
    const float* u  = (const float*)d_in[3];   // [512]
    float* out = (float*)d_out;                // [65536 output | 262144 alphas]
    unsigned short* Wswz = (unsigned short*)d_ws;   // 512 KiB bf16 swizzled W

    k_wswz<<<128, 256, 0, stream>>>(W, Wswz);
    k_gemm_vu<<<M_TOK / 64, 256, 0, stream>>>(X, Wswz, bb, u, out + 65536);
    k_softmax<<<BDIM, 256, 0, stream>>>(out);
    hipMemsetAsync(d_out, 0, 65536 * sizeof(float), stream);
    k_wsum<<<BDIM * 8, 256, 0, stream>>>(X, out);
}

// Round 2
// 798.126 us; speedup vs baseline: 1.0788x; 1.0788x over previous
//
#include <hip/hip_runtime.h>
#include <hip/hip_bf16.h>
#include <math.h>

// B=128, S=2048, H=512, A=512. M = B*S = 262144 tokens.
// out = (output [128,512], alphas [128,2048]) fp32 concat: 65536 + 262144.
//
// Flash-style single-X-pass plan:
//   k_wswz      : W fp32 -> bf16, pre-swizzled into MFMA B-frag order (ws[0:512KiB])
//   k_gemm_fused: per 64-row chunk: GEMM+tanh+dot(u) -> vu, chunk softmax
//                 (m,l), chunk-partial weighted sum o[512] from the bf16 LDS
//                 X tile. Partials (o[512],m,l) -> ws. vu -> alphas slot.
//   k_combine   : merge 32 chunks/batch -> output[b,h]; (M,inv) -> ws params
//   k_alphas    : alphas = exp(vu - M_b) * inv_b, in place.

#define M_TOK 262144
#define HDIM 512
#define ADIM 512
#define SDIM 2048
#define BDIM 128

#define WSWZ_FLOATS 131072          // 512 KiB bf16 W = 131072 floats of ws
#define PART_STRIDE 514             // o[512], m, l
#define NCHUNK 4096                 // M_TOK / 64

typedef __attribute__((ext_vector_type(8))) short short8;   // 8 bf16 (4 VGPRs)
typedef __attribute__((ext_vector_type(4))) float f32x4;    // 4 fp32 acc

static __device__ __forceinline__ unsigned short f2bf(float f) {
    unsigned u = __builtin_bit_cast(unsigned, f);
    unsigned rnd = 0x7FFFu + ((u >> 16) & 1u);
    return (unsigned short)((u + rnd) >> 16);
}

// ---------------------------------------------------------------------------
// k0: W [512][512] fp32 -> bf16 in 16x16x32 B-fragment order.
// Fragment (kb,nb): lane holds W[kb*32 + (lane>>4)*8 + j][nb*16 + (lane&15)].
// ---------------------------------------------------------------------------
__global__ void k_wswz(const float* __restrict__ W, unsigned short* __restrict__ Wswz) {
    int t = blockIdx.x * 256 + threadIdx.x;   // 32768 threads
    int lane = t & 63;
    int frag = t >> 6;                        // frag = kb*32 + nb
    int kb = frag >> 5;
    int nb = frag & 31;
    int n  = nb * 16 + (lane & 15);
    int k0 = kb * 32 + (lane >> 4) * 8;
    short8 s;
#pragma unroll
    for (int j = 0; j < 8; ++j)
        s[j] = (short)f2bf(W[(k0 + j) * ADIM + n]);
    reinterpret_cast<short8*>(Wswz)[t] = s;
}

// ---------------------------------------------------------------------------
// k1: fused GEMM + tanh·u -> vu, chunk softmax, chunk-partial weighted sum.
// 64 token-rows per block; X staged once (bf16 LDS); 4 waves split N=512.
// ---------------------------------------------------------------------------
__global__ __launch_bounds__(256, 2)
void k_gemm_fused(const float* __restrict__ X, const unsigned short* __restrict__ Wswz,
                  const float* __restrict__ bvec, const float* __restrict__ u,
                  float* __restrict__ vu, float* __restrict__ part) {
    __shared__ __align__(16) unsigned short Xs[64][520];
    __shared__ float vured[4][64];
    __shared__ float e_lds[64];

    const int tid  = threadIdx.x;
    const int lane = tid & 63;
    const int wave = tid >> 6;
    const int lm   = lane & 15;
    const int quad = lane >> 4;
    const int r0   = blockIdx.x * 64;
    float* pblk    = part + (size_t)blockIdx.x * PART_STRIDE;

    // ---- stage X[r0:r0+64][0:512] fp32 -> bf16 LDS (coalesced float4) ----
    const float4* Xp = reinterpret_cast<const float4*>(X + (size_t)r0 * HDIM);
#pragma unroll 8
    for (int it = 0; it < 32; ++it) {
        int idx  = it * 256 + tid;
        int row  = idx >> 7;
        int col4 = idx & 127;
        float4 v = Xp[idx];
        unsigned lo = (unsigned)f2bf(v.x) | ((unsigned)f2bf(v.y) << 16);
        unsigned hi = (unsigned)f2bf(v.z) | ((unsigned)f2bf(v.w) << 16);
        unsigned* d = reinterpret_cast<unsigned*>(&Xs[row][col4 * 4]);
        d[0] = lo; d[1] = hi;
    }
    __syncthreads();

    // ---- GEMM: per wave 4(M) x 8(N) C-frags, B streamed from L2, 1-kb prefetch
    const short8* wbl = reinterpret_cast<const short8*>(Wswz) + lane + wave * 512;

    f32x4 acc[4][8];
#pragma unroll
    for (int i = 0; i < 4; ++i)
#pragma unroll
        for (int j = 0; j < 8; ++j)
            acc[i][j] = (f32x4){0.f, 0.f, 0.f, 0.f};

    short8 bcur[8], bnxt[8];
#pragma unroll
    for (int j = 0; j < 8; ++j) bcur[j] = wbl[j * 64];

    for (int kb = 0; kb < 16; ++kb) {
        if (kb < 15) {
#pragma unroll
            for (int j = 0; j < 8; ++j) bnxt[j] = wbl[(kb + 1) * 2048 + j * 64];
        }
        short8 a[4];
#pragma unroll
        for (int i = 0; i < 4; ++i)
            a[i] = *reinterpret_cast<const short8*>(&Xs[i * 16 + lm][kb * 32 + quad * 8]);
#pragma unroll
        for (int i = 0; i < 4; ++i)
#pragma unroll
            for (int j = 0; j < 8; ++j)
                acc[i][j] = __builtin_amdgcn_mfma_f32_16x16x32_bf16(a[i], bcur[j], acc[i][j], 0, 0, 0);
#pragma unroll
        for (int j = 0; j < 8; ++j) bcur[j] = bnxt[j];
    }

    // ---- epilogue A: tanh(acc + b) dot u, reduce to per-row vu ----
    float vus[16];
#pragma unroll
    for (int q = 0; q < 16; ++q) vus[q] = 0.f;
    const int colbase = wave * 128 + lm;
#pragma unroll
    for (int j = 0; j < 8; ++j) {
        int col  = colbase + j * 16;
        float uu = u[col];
        float bb = bvec[col];
#pragma unroll
        for (int i = 0; i < 4; ++i)
#pragma unroll
            for (int r = 0; r < 4; ++r) {
                float x = acc[i][j][r] + bb;
                float e = __expf(2.0f * x);        // inf-safe tanh
                float t = 1.0f - 2.0f / (e + 1.0f);
                vus[i * 4 + r] += t * uu;
            }
    }
#pragma unroll
    for (int m = 1; m <= 8; m <<= 1) {
#pragma unroll
        for (int q = 0; q < 16; ++q)
            vus[q] += __shfl_xor(vus[q], m, 64);
    }
    if (lm == 0) {
#pragma unroll
        for (int i = 0; i < 4; ++i)
#pragma unroll
            for (int r = 0; r < 4; ++r)
                vured[wave][i * 16 + quad * 4 + r] = vus[i * 4 + r];
    }
    __syncthreads();

    // ---- epilogue B: chunk softmax (m, l, e_s) by one wave ----
    if (tid < 64) {
        float v = (vured[0][tid] + vured[1][tid] + vured[2][tid] + vured[3][tid])
                  * 0.044194173824159216f;         // 1/sqrt(512)
        vu[r0 + tid] = v;
        float m = v;
#pragma unroll
        for (int j = 1; j <= 32; j <<= 1) m = fmaxf(m, __shfl_xor(m, j, 64));
        float e = __expf(v - m);
        e_lds[tid] = e;
        float l = e;
#pragma unroll
        for (int j = 1; j <= 32; j <<= 1) l += __shfl_xor(l, j, 64);
        if (tid == 0) { pblk[512] = m; pblk[513] = l; }
    }
    __syncthreads();

    // ---- epilogue C: o[h] = sum_s e_s * x[s][h], from the bf16 LDS tile ----
    float o0 = 0.f, o1 = 0.f;
    const int c2 = tid * 2;                        // two adjacent columns
#pragma unroll 8
    for (int s = 0; s < 64; ++s) {
        unsigned uu = *reinterpret_cast<const unsigned*>(&Xs[s][c2]);
        float e  = e_lds[s];                       // LDS broadcast
        float xl = __builtin_bit_cast(float, uu << 16);
        float xh = __builtin_bit_cast(float, uu & 0xFFFF0000u);
        o0 = fmaf(e, xl, o0);
        o1 = fmaf(e, xh, o1);
    }
    *reinterpret_cast<float2*>(&pblk[c2]) = make_float2(o0, o1);
}

// ---------------------------------------------------------------------------
// k2: merge 32 chunks per batch -> output[b,:]; write (M, inv) params.
// ---------------------------------------------------------------------------
__global__ __launch_bounds__(256)
void k_combine(const float* __restrict__ part, float* __restrict__ out,
               float* __restrict__ params) {
    const int b = blockIdx.x, tid = threadIdx.x;
    __shared__ float wch[32];
    __shared__ float sinv;
    const float* pb = part + (size_t)b * 32 * PART_STRIDE;
    if (tid < 32) {
        float m = pb[tid * PART_STRIDE + 512];
        float l = pb[tid * PART_STRIDE + 513];
        float M = m;
#pragma unroll
        for (int j = 1; j <= 16; j <<= 1) M = fmaxf(M, __shfl_xor(M, j, 32));
        float w  = __expf(m - M);
        float lw = l * w;
#pragma unroll
        for (int j = 1; j <= 16; j <<= 1) lw += __shfl_xor(lw, j, 32);
        wch[tid] = w;
        if (tid == 0) {
            float inv = 1.0f / (lw + 1e-10f);
            sinv = inv;
            params[b] = M;
            params[BDIM + b] = inv;
        }
    }
    __syncthreads();
    float inv = sinv;
    float o0 = 0.f, o1 = 0.f;
    const int h = tid * 2;
#pragma unroll 8
    for (int c = 0; c < 32; ++c) {
        float w = wch[c];
        float2 v = *reinterpret_cast<const float2*>(&pb[c * PART_STRIDE + h]);
        o0 = fmaf(w, v.x, o0);
        o1 = fmaf(w, v.y, o1);
    }
    out[b * HDIM + h]     = o0 * inv;
    out[b * HDIM + h + 1] = o1 * inv;
}

// ---------------------------------------------------------------------------
// k3: alphas = exp(vu - M_b) * inv_b, in place in the alphas slot.
// ---------------------------------------------------------------------------
__global__ void k_alphas(float* __restrict__ vu, const float* __restrict__ params) {
    int i = blockIdx.x * 256 + threadIdx.x;
    int b = i >> 11;                               // / 2048
    vu[i] = __expf(vu[i] - params[b]) * params[BDIM + b];
}

extern "C" void kernel_launch(void* const* d_in, const int* in_sizes, int n_in,
                              void* d_out, int out_size, void* d_ws, size_t ws_size,
                              hipStream_t stream) {
    const float* X  = (const float*)d_in[0];   // [128,2048,512]
    const float* W  = (const float*)d_in[1];   // [512,512]
    const float* bb = (const float*)d_in[2];   // [512]
    const float* u  = (const float*)d_in[3];   // [512]
    float* out = (float*)d_out;                // [65536 output | 262144 alphas]

    unsigned short* Wswz = (unsigned short*)d_ws;
    float* part   = (float*)d_ws + WSWZ_FLOATS;                       // 4096*514 floats
    float* params = (float*)d_ws + WSWZ_FLOATS + NCHUNK * PART_STRIDE; // 256 floats

    k_wswz<<<128, 256, 0, stream>>>(W, Wswz);
    k_gemm_fused<<<NCHUNK, 256, 0, stream>>>(X, Wswz, bb, u, out + 65536, part);
    k_combine<<<BDIM, 256, 0, stream>>>(part, out, params);
    k_alphas<<<M_TOK / 256, 256, 0, stream>>>(out + 65536, params);
}